// Round 7
// baseline (412.296 us; speedup 1.0000x reference)
//
#include <hip/hip_runtime.h>
#include <hip/hip_bf16.h>
#include <cstdint>
#include <cstddef>

#define NN     8192
#define INF_   256
#define OUTF   128
#define ALPHA  0.2f
#define LOG2E  1.4426950408889634f
#define JSPLIT 8
#define CHUNK  (NN / JSPLIT)     // 1024 j per block
#define NS     (CHUNK / 32)      // 32 steps of 32 j

typedef __bf16 bf16;
typedef unsigned int u32;
typedef unsigned short u16;
typedef unsigned long long u64;
typedef __attribute__((ext_vector_type(8))) __bf16 bf16x8;
typedef __attribute__((ext_vector_type(4))) float f32x4;
typedef __attribute__((ext_vector_type(4))) int i32x4;
typedef __attribute__((ext_vector_type(4))) unsigned int u32x4;
typedef __attribute__((ext_vector_type(8))) unsigned short u16x8;
typedef __attribute__((ext_vector_type(4))) unsigned short u16x4;

// async global->LDS, 16 B per lane (dest = wave-uniform base + lane*16)
typedef __attribute__((address_space(1))) const unsigned int gas_u32;
typedef __attribute__((address_space(3))) unsigned int las_u32;
static __device__ __forceinline__ void gll16(const void* g, void* l)
{
    __builtin_amdgcn_global_load_lds((gas_u32*)g, (las_u32*)l, 16, 0, 0);
}

#define MEMFENCE asm volatile("" ::: "memory")

// ---------------------------------------------------------------------------
// In-kernel dtype detect (replaces the gat_detect dispatch; R7 fused).
// Wave 0 scans x's first 2048 u16 as bf16: fp32 storage -> mantissa fragments
// with huge exponents; bf16 storage -> N(0,1). Result broadcast via LDS.
// Identical decision logic to the standalone kernel (validated R0-R6).
// ---------------------------------------------------------------------------
static __device__ __forceinline__ void detect_wave0(const u16* xr, int tid, int* sflag)
{
    if (tid < 64) {
        float m = 0.f;
        #pragma unroll
        for (int t = 0; t < 32; ++t) {
            const u16 u = xr[tid * 32 + t];
            const float v = fabsf((float)__builtin_bit_cast(bf16, u));
            if (v == v) m = fmaxf(m, v);
        }
        #pragma unroll
        for (int d = 1; d < 64; d <<= 1) m = fmaxf(m, __shfl_xor(m, d));
        if (tid == 0) *sflag = (m > 100.f) ? 1 : 0;
    }
}

// ---------------------------------------------------------------------------
// Projection, v7-fused: ONE dispatch does dtype-detect + trans-transpose
// (formerly gat_tt x2) + h = x @ trans MFMA + e1/e2 + HTt tiled write.
// Dtype branches are wave-uniform (sflag) -> no divergence cost.
// trans transpose: read trans[k][n] coalesced along n, write TTs[n][k]
// (the transpose happens in the LDS write pattern; ~128 KB L2-hot/block).
// ---------------------------------------------------------------------------
__global__ __launch_bounds__(256, 1)
void gat_proj(const void* __restrict__ xv, const void* __restrict__ tv,
              const void* __restrict__ awv,
              bf16* __restrict__ HTt, float* __restrict__ e1c, float* __restrict__ e2c)
{
    __shared__ int   sflag;
    __shared__ bf16  xs[32][264];
    __shared__ bf16  TTs[128][264];
    __shared__ float hl[32][129];

    const int tid  = threadIdx.x;
    const int wave = tid >> 6;
    const int lane = tid & 63;
    const int m    = lane & 15;
    const int q    = lane >> 4;
    const int i0   = blockIdx.x * 32;

    detect_wave0((const u16*)xv, tid, &sflag);
    __syncthreads();
    const bool isf = (sflag != 0);

    if (isf) {   // ---- fp32 inputs
        const float* x = (const float*)xv;
        #pragma unroll
        for (int it = 0; it < 8; ++it) {
            const int e = it * 1024 + tid * 4;
            const f32x4 v = *(const f32x4*)(x + (size_t)i0 * INF_ + e);
            u16x4 p;
            #pragma unroll
            for (int t = 0; t < 4; ++t) p[t] = __builtin_bit_cast(u16, (bf16)v[t]);
            *(u16x4*)&xs[e >> 8][e & 255] = p;
        }
        const float* tr = (const float*)tv;
        const int n4 = (tid & 31) * 4, k2 = tid >> 5;
        #pragma unroll
        for (int kk = 0; kk < 32; ++kk) {
            const int k = kk * 8 + k2;
            const f32x4 v = *(const f32x4*)(tr + k * OUTF + n4);
            #pragma unroll
            for (int j = 0; j < 4; ++j) TTs[n4 + j][k] = (bf16)v[j];
        }
    } else {     // ---- bf16 inputs
        const u16* x = (const u16*)xv;
        #pragma unroll
        for (int it = 0; it < 8; ++it) {
            const int e = it * 1024 + tid * 4;
            *(u16x4*)&xs[e >> 8][e & 255] = *(const u16x4*)(x + (size_t)i0 * INF_ + e);
        }
        const u16* tr = (const u16*)tv;
        const int n8 = (tid & 15) * 8, k2 = tid >> 4;
        #pragma unroll
        for (int kk = 0; kk < 16; ++kk) {
            const int k = kk * 16 + k2;
            const u16x8 v = *(const u16x8*)(tr + k * OUTF + n8);
            #pragma unroll
            for (int j = 0; j < 8; ++j) TTs[n8 + j][k] = __builtin_bit_cast(bf16, v[j]);
        }
    }
    __syncthreads();

    const int rh = wave & 1, fh = wave >> 1;
    f32x4 acc[4] = {};
    #pragma unroll
    for (int ks = 0; ks < INF_; ks += 32) {
        const bf16x8 a = *(const bf16x8*)&xs[rh * 16 + m][ks + q * 8];
        #pragma unroll
        for (int tn = 0; tn < 4; ++tn) {
            const bf16x8 b = *(const bf16x8*)&TTs[fh * 64 + tn * 16 + m][ks + q * 8];
            acc[tn] = __builtin_amdgcn_mfma_f32_16x16x32_bf16(a, b, acc[tn], 0, 0, 0);
        }
    }

    #pragma unroll
    for (int tn = 0; tn < 4; ++tn)
        #pragma unroll
        for (int r = 0; r < 4; ++r)
            hl[rh * 16 + q * 4 + r][fh * 64 + tn * 16 + m] = acc[tn][r];
    __syncthreads();

    {   // e1/e2
        const int r = tid >> 3, seg = tid & 7;
        float s1 = 0.f, s2 = 0.f;
        if (isf) {
            const float* aw = (const float*)awv;
            #pragma unroll
            for (int u = 0; u < 16; ++u) {
                const float hv = hl[r][seg * 16 + u];
                s1 += hv * aw[seg * 16 + u];
                s2 += hv * aw[OUTF + seg * 16 + u];
            }
        } else {
            const bf16* aw = (const bf16*)awv;
            #pragma unroll
            for (int u = 0; u < 16; ++u) {
                const float hv = hl[r][seg * 16 + u];
                s1 += hv * (float)aw[seg * 16 + u];
                s2 += hv * (float)aw[OUTF + seg * 16 + u];
            }
        }
        #pragma unroll
        for (int d = 1; d < 8; d <<= 1) {
            s1 += __shfl_xor(s1, d);
            s2 += __shfl_xor(s2, d);
        }
        if (seg == 0) {
            e1c[i0 + r] = s1 * LOG2E;
            e2c[i0 + r] = s2 * LOG2E;
        }
    }

    {   // HTt tiled write: HTt[i>>5][n][i&31]
        const int n = tid >> 1, ih = tid & 1;
        u16x8 p0, p1;
        #pragma unroll
        for (int v = 0; v < 8; ++v) {
            p0[v] = __builtin_bit_cast(u16, (bf16)hl[ih * 16 + v][n]);
            p1[v] = __builtin_bit_cast(u16, (bf16)hl[ih * 16 + 8 + v][n]);
        }
        bf16* base = HTt + (size_t)blockIdx.x * 4096 + n * 32 + ih * 16;
        *(u16x8*)base       = p0;
        *(u16x8*)(base + 8) = p1;
    }
}

// ---------------------------------------------------------------------------
// Masked-softmax-attention partials (unchanged from R6's proven v7 form):
// counted-vmcnt pipeline, 4 LDS tile buffers, adj reg-prefetch, JSPLIT=8,
// grid 1024 = 4 blocks/CU one pass, jc = bid&7 XCD-pins the HT slice.
// ---------------------------------------------------------------------------
__global__ __launch_bounds__(256, 4)
void gat_attn(const int* __restrict__ adj, const bf16* __restrict__ HTt,
              const float* __restrict__ e1c, const float* __restrict__ e2c,
              float* __restrict__ numP, float* __restrict__ denP)
{
    __shared__ bf16  hts[4][4096];   // 4 x 8 KB HT step tiles
    __shared__ float e2s[CHUNK];     // 4 KB e2 slice (pre-scaled by log2e)

    const int tid  = threadIdx.x;
    const int wave = tid >> 6;
    const int lane = tid & 63;
    const int m    = lane & 15;
    const int q    = lane >> 4;
    const int jc   = blockIdx.x & (JSPLIT - 1);
    const int ig   = blockIdx.x / JSPLIT;
    const int rbase = ig * 64 + wave * 16;   // one 16-row group per wave
    const int j0    = jc * CHUNK;

    const int hn = tid & 127;
    const int hq = tid >> 7;
    const bf16* tbase = HTt + (size_t)(jc * NS) * 4096;

    auto stageHT = [&](int s, int b) {
        const bf16* ts = tbase + (size_t)s * 4096;
        gll16(ts + hn * 32 + hq * 8,       &hts[b][(wave * 64) * 8]);
        gll16(ts + hn * 32 + (hq + 2) * 8, &hts[b][(256 + wave * 64) * 8]);
    };

    // e1/e2 first: their loads drain before the counted region starts
    const float e1 = e1c[rbase + m];
    {
        const f32x4 ev = *(const f32x4*)(e2c + j0 + tid * 4);
        *(f32x4*)&e2s[tid * 4] = ev;
    }
    MEMFENCE;

    const int* ap = adj + (size_t)(rbase + m) * NN + j0 + q * 8;

    f32x4 acc[8] = {};
    float rs = 0.f;
    i32x4 adjv[4][2];   // distance-4 adj prefetch, slot = s&3 (static idx)

    stageHT(0, 0);
    stageHT(1, 1);
    MEMFENCE;
    #pragma unroll
    for (int s = 0; s < 4; ++s) {
        adjv[s][0] = *(const i32x4*)(ap + s * 32);
        adjv[s][1] = *(const i32x4*)(ap + s * 32 + 4);
    }
    asm volatile("s_waitcnt vmcnt(6) lgkmcnt(0)" ::: "memory");
    __builtin_amdgcn_s_barrier();
    MEMFENCE;

    #pragma unroll
    for (int s = 0; s < NS; ++s) {
        const int cur = s & 3;

        if (s < NS - 2) stageHT(s + 2, (s + 2) & 3);
        MEMFENCE;

        const f32x4 e2a = *(const f32x4*)&e2s[s * 32 + q * 8];
        const f32x4 e2b = *(const f32x4*)&e2s[s * 32 + q * 8 + 4];

        bf16x8 af;   // A[m][k=q*8+t], leaky-relu in log2 domain, adj-masked
        #pragma unroll
        for (int t = 0; t < 4; ++t) {
            float sv = e1 + e2a[t];
            sv = fmaxf(sv, ALPHA * sv);
            const float p = (adjv[cur][0][t] != 0) ? __builtin_amdgcn_exp2f(sv) : 0.f;
            rs += p;
            af[t] = (bf16)p;
        }
        #pragma unroll
        for (int t = 0; t < 4; ++t) {
            float sv = e1 + e2b[t];
            sv = fmaxf(sv, ALPHA * sv);
            const float p = (adjv[cur][1][t] != 0) ? __builtin_amdgcn_exp2f(sv) : 0.f;
            rs += p;
            af[4 + t] = (bf16)p;
        }

        if (s < NS - 4) {
            adjv[cur][0] = *(const i32x4*)(ap + (s + 4) * 32);
            adjv[cur][1] = *(const i32x4*)(ap + (s + 4) * 32 + 4);
        }
        MEMFENCE;

        #pragma unroll
        for (int t = 0; t < 8; ++t) {
            const bf16x8 b = *(const bf16x8*)&hts[cur][q * 1024 + (t * 16 + m) * 8];
            acc[t] = __builtin_amdgcn_mfma_f32_16x16x32_bf16(af, b, acc[t], 0, 0, 0);
        }

        if (s < NS - 4) {
            asm volatile("s_waitcnt vmcnt(6)" ::: "memory");
            __builtin_amdgcn_s_barrier();
            MEMFENCE;
        } else if (s < NS - 1) {
            asm volatile("s_waitcnt vmcnt(0)" ::: "memory");
            __builtin_amdgcn_s_barrier();
            MEMFENCE;
        }
    }

    rs += __shfl_xor(rs, 16);
    rs += __shfl_xor(rs, 32);
    if (lane < 16) denP[(size_t)jc * NN + rbase + m] = rs;

    #pragma unroll
    for (int t = 0; t < 8; ++t)
        #pragma unroll
        for (int r = 0; r < 4; ++r)
            numP[((size_t)jc * NN + rbase + q * 4 + r) * OUTF + t * 16 + m] = acc[t][r];
}

// ---------------------------------------------------------------------------
// Finalize, v7-fused: out = elu( (sum_s numP) / (sum_s denP) ).
// Does its own dtype detect (no flag buffer / no detect dispatch).
// ---------------------------------------------------------------------------
__global__ __launch_bounds__(256)
void gat_fin(const float* __restrict__ numP, const float* __restrict__ denP,
             const void* __restrict__ xv, void* __restrict__ outv)
{
    __shared__ int sflag;
    detect_wave0((const u16*)xv, threadIdx.x, &sflag);
    __syncthreads();

    const int g  = blockIdx.x * 256 + threadIdx.x;   // one thread per 4 elems
    const int i  = g >> 5;
    const int c4 = g & 31;
    float d = 0.f;
    f32x4 v = {0.f, 0.f, 0.f, 0.f};
    #pragma unroll
    for (int s = 0; s < JSPLIT; ++s) {
        d += denP[(size_t)s * NN + i];
        const f32x4 u = *(const f32x4*)(numP + ((size_t)s * NN + i) * OUTF + c4 * 4);
        #pragma unroll
        for (int t = 0; t < 4; ++t) v[t] += u[t];
    }
    #pragma unroll
    for (int t = 0; t < 4; ++t) {
        const float u = v[t] / d;
        v[t] = (u > 0.f) ? u : __builtin_amdgcn_exp2f(u * LOG2E) - 1.f;  // elu
    }
    const size_t off = (size_t)i * OUTF + c4 * 4;
    if (sflag) {
        *(f32x4*)((float*)outv + off) = v;
    } else {
        u16x4 pk;
        #pragma unroll
        for (int t = 0; t < 4; ++t)
            pk[t] = __builtin_bit_cast(u16, (bf16)v[t]);
        *(u16x4*)((__hip_bfloat16*)outv + off) = pk;
    }
}

// ---------------------------------------------------------------------------
extern "C" void kernel_launch(void* const* d_in, const int* in_sizes, int n_in,
                              void* d_out, int out_size, void* d_ws, size_t ws_size,
                              hipStream_t stream)
{
    const int* adj = (const int*)d_in[1];

    // ws layout (bytes): HTt 2MB | e1c 32KB | e2c 32KB | numP 32MB | denP 256KB
    char* w = (char*)d_ws;
    bf16*  HTt   = (bf16*)w;   w += (size_t)OUTF * NN * 2;
    float* e1c   = (float*)w;  w += NN * 4;
    float* e2c   = (float*)w;  w += NN * 4;
    float* numP  = (float*)w;  w += (size_t)JSPLIT * NN * OUTF * 4;
    float* denP  = (float*)w;

    // 3 dispatches total (was 7): R7 targets ~12 us/dispatch boundary cost.
    gat_proj<<<NN / 32, 256, 0, stream>>>(d_in[0], d_in[2], d_in[3], HTt, e1c, e2c);

    gat_attn<<<(NN / 64) * JSPLIT, 256, 0, stream>>>(adj, HTt, e1c, e2c, numP, denP);

    gat_fin<<<NN * OUTF / 4 / 256, 256, 0, stream>>>(numP, denP, d_in[0], d_out);
}